// Round 5
// baseline (1467.884 us; speedup 1.0000x reference)
//
#include <hip/hip_runtime.h>
#include <stdint.h>

typedef unsigned short u16;

#define IN_F   4096
#define OUT_F  11008
#define M_TOT  8192   /* 4*2048 */

__device__ __constant__ float NF4_TAB[16] = {
    -1.0f, -0.6961928009986877f, -0.5250730514526367f, -0.39491748809814453f,
    -0.28444138169288635f, -0.18477343022823334f, -0.09105003625154495f, 0.0f,
    0.07958029955625534f, 0.16093020141124725f, 0.24611230194568634f,
    0.33791524171829224f, 0.44070982933044434f, 0.5626170039176941f,
    0.7229568362236023f, 1.0f};

static __device__ __forceinline__ unsigned f2bf(float f) {
  unsigned u = __float_as_uint(f);
  u += 0x7fffu + ((u >> 16) & 1u);   // round-to-nearest-even
  return u >> 16;
}

// ---------------- dequant W: codes(int32)+absmax -> bf16, 8 elems/thread ----
__global__ __launch_bounds__(256) void dequant_w_kernel(
    const int* __restrict__ codes, const float* __restrict__ absmax,
    uint4* __restrict__ wout, int n8) {
  __shared__ float lut[16];
  if (threadIdx.x < 16) lut[threadIdx.x] = NF4_TAB[threadIdx.x];
  __syncthreads();
  int t = blockIdx.x * 256 + threadIdx.x;
  if (t >= n8) return;
  const int4* cp = (const int4*)codes + (size_t)t * 2;
  int4 c0 = cp[0];
  int4 c1 = cp[1];
  float am = absmax[t >> 3];          // 8 elems all inside one 64-block
  unsigned h0 = f2bf(lut[c0.x] * am) | (f2bf(lut[c0.y] * am) << 16);
  unsigned h1 = f2bf(lut[c0.z] * am) | (f2bf(lut[c0.w] * am) << 16);
  unsigned h2 = f2bf(lut[c1.x] * am) | (f2bf(lut[c1.y] * am) << 16);
  unsigned h3 = f2bf(lut[c1.z] * am) | (f2bf(lut[c1.w] * am) << 16);
  wout[t] = make_uint4(h0, h1, h2, h3);
}

// ---------------- convert x: fp32 -> bf16, 8 elems/thread -------------------
__global__ __launch_bounds__(256) void convert_x_kernel(
    const float4* __restrict__ x, uint4* __restrict__ xout, int n8) {
  int t = blockIdx.x * 256 + threadIdx.x;
  if (t >= n8) return;
  float4 a = x[(size_t)t * 2];
  float4 b = x[(size_t)t * 2 + 1];
  unsigned h0 = f2bf(a.x) | (f2bf(a.y) << 16);
  unsigned h1 = f2bf(a.z) | (f2bf(a.w) << 16);
  unsigned h2 = f2bf(b.x) | (f2bf(b.y) << 16);
  unsigned h3 = f2bf(b.z) | (f2bf(b.w) << 16);
  xout[t] = make_uint4(h0, h1, h2, h3);
}

// ---------------- 128x256 BK=32, 4 waves, 128x64/wave, 2 blocks/CU ----------
// C[M,N] = A[M,K] * B[N,K]^T.  4 waves each own 128x64 out (LDS B/FLOP =
// 0.0234 -> 79 B/cyc at full MFMA rate, under the 85 B/cyc LDS ceiling; the
// r3/r4 64x64 tiles needed 105 -> LDS-bound at ~46% MfmaUtil).  acc = 128
// AGPR + ~80 VGPR -> 256 bucket -> 2 waves/SIMD -> 2 independent blocks/CU:
// one block's vmcnt/barrier stalls hide under the other's MFMA cluster.
// LDS = 3 ring slots x 24 KiB = 72 KiB.  Step t: stage tile t+2 first (6
// global_load_lds), 12 ds_read_b128, 32 MFMA, vmcnt(6) (never 0), barrier.
// Swizzle involution keyed on (row>>1)&3 (r4-verified, 0 conflicts).
// Bijective XCD swizzle: 2752 = 8 * 344, nb-fastest -> A panel L2-resident.
typedef __attribute__((ext_vector_type(8))) short short8;
typedef __attribute__((ext_vector_type(4))) float f32x4;

static __device__ __forceinline__ void async_copy16(const u16* g, u16* l) {
  __builtin_amdgcn_global_load_lds(
      (const __attribute__((address_space(1))) unsigned int*)g,
      (__attribute__((address_space(3))) unsigned int*)l, 16, 0, 0);
}

// Stage K-tile KT into ring slot LP: A 128x32 (2 loads) + B 256x32 (4 loads).
// Each load: 64 lanes x 16B = 16 rows of 64B, linear LDS dest; global col is
// pre-swizzled (slot ^ (row>>1)&3) so store/read form an involution.
#define STAGE(LP, KT)                                                        \
  do {                                                                       \
    const u16* ga_ = agp + (size_t)(KT) * 32;                                \
    const u16* gb_ = bgp + (size_t)(KT) * 32;                                \
    async_copy16(ga_,                      (LP) + wave * 1024);              \
    async_copy16(ga_ + (size_t)16 * IN_F,  (LP) + wave * 1024 + 512);        \
    async_copy16(gb_,                      (LP) + 4096 + wave * 2048);       \
    async_copy16(gb_ + (size_t)16 * IN_F,  (LP) + 4096 + wave * 2048 + 512); \
    async_copy16(gb_ + (size_t)32 * IN_F,  (LP) + 4096 + wave * 2048 + 1024);\
    async_copy16(gb_ + (size_t)48 * IN_F,  (LP) + 4096 + wave * 2048 + 1536);\
  } while (0)

__global__ __launch_bounds__(256, 2) void gemm128x256_bt_bf16_kernel(
    const u16* __restrict__ A,   // [M_TOT, IN_F] bf16 bits
    const u16* __restrict__ B,   // [OUT_F, IN_F] bf16 bits
    float* __restrict__ C) {     // [M_TOT, OUT_F]
  constexpr int K  = IN_F;
  constexpr int N  = OUT_F;
  constexpr int NT = K / 32;                 // 128 K-tiles
  __shared__ u16 lds[3][(128 + 256) * 32];   // A:[0,4096) B:[4096,12288) elems

  const int tid   = threadIdx.x;
  const int wave  = tid >> 6;                // 0..3 (N dir, 64 cols each)
  const int lane  = tid & 63;
  const int row16 = lane & 15;
  const int quad  = lane >> 4;
  const int rsw   = (quad ^ ((row16 >> 1) & 3)) << 3;  // swizzled k-slot (elems)

  // T1: bijective XCD swizzle. nwg = 2752 = 8 * 344 (= 8 mb-rows of 43 nb).
  const int orig = blockIdx.x;
  const int tile = (orig & 7) * 344 + (orig >> 3);
  const int mb = tile / 43, nb = tile % 43;
  const int m0 = mb * 128, n0 = nb * 256;

  // staging: lane l covers LDS row base + (l>>2), 16B slot (l&3);
  // pre-swizzled global col = ((l&3) ^ ((l>>3)&3)) * 8 elems
  // (valid because every load's row base is a multiple of 16).
  const int srow = lane >> 2;
  const int scol = ((lane & 3) ^ ((lane >> 3) & 3)) << 3;
  const u16* agp = A + (size_t)(m0 + wave * 32 + srow) * K + scol;
  const u16* bgp = B + (size_t)(n0 + wave * 64 + srow) * K + scol;

  f32x4 acc[8][4] = {};

  u16* s0 = &lds[0][0];
  u16* s1 = &lds[1][0];
  u16* s2 = &lds[2][0];

  // prologue: tiles 0,1 into slots 0,1. Wait slot0's 6 (slot1's 6 in flight).
  STAGE(s0, 0);
  STAGE(s1, 1);
  asm volatile("s_waitcnt vmcnt(6)\n\ts_barrier" ::: "memory");

  for (int t = 0; t < NT; ++t) {
    const int tn = (t + 2 < NT) ? t + 2 : NT - 1;  // clamped redundant restage
    STAGE(s2, tn);                                  // issue-early (T14)
    short8 af[8], bf[4];
#pragma unroll
    for (int i = 0; i < 8; ++i)
      af[i] = *(const short8*)&s0[(i * 16 + row16) * 32 + rsw];
#pragma unroll
    for (int j = 0; j < 4; ++j)
      bf[j] = *(const short8*)&s0[4096 + (wave * 64 + j * 16 + row16) * 32 + rsw];
    __builtin_amdgcn_s_setprio(1);
#pragma unroll
    for (int i = 0; i < 8; ++i)
#pragma unroll
      for (int j = 0; j < 4; ++j)
        acc[i][j] = __builtin_amdgcn_mfma_f32_16x16x32_bf16(
            af[i], bf[j], acc[i][j], 0, 0, 0);
    __builtin_amdgcn_s_setprio(0);
    // tile t+1's 6 loads (issued last step) done; tile t+2's 6 stay in flight.
    asm volatile("s_waitcnt vmcnt(6)\n\ts_barrier" ::: "memory");
    u16* tmp = s0; s0 = s1; s1 = s2; s2 = tmp;
  }
  asm volatile("s_waitcnt vmcnt(0)" ::: "memory");  // drain dummy tail stages

  // Epilogue: C/D layout col = lane&15, row = quad*4 + reg  [m89/m91]
#pragma unroll
  for (int i = 0; i < 8; ++i)
#pragma unroll
    for (int j = 0; j < 4; ++j)
#pragma unroll
      for (int r = 0; r < 4; ++r)
        C[(size_t)(m0 + i * 16 + quad * 4 + r) * N +
          (n0 + wave * 64 + j * 16 + row16)] = acc[i][j][r];
}

// ---------------- fallback (ws too small): slow but correct -----------------
__global__ void fallback_kernel(const float* __restrict__ x,
                                const int* __restrict__ codes,
                                const float* __restrict__ absmax,
                                float* __restrict__ out) {
  __shared__ float lut[16];
  __shared__ float xs[16][17];
  __shared__ float ws[16][17];
  const int tx = threadIdx.x, ty = threadIdx.y;
  if (ty == 0 && tx < 16) lut[tx] = NF4_TAB[tx];
  __syncthreads();
  const int m  = blockIdx.y * 16 + ty;
  const int n0 = blockIdx.x * 16;
  float acc = 0.f;
  for (int k0 = 0; k0 < IN_F; k0 += 16) {
    xs[ty][tx] = x[(size_t)m * IN_F + k0 + tx];
    int idx = (n0 + ty) * IN_F + k0 + tx;
    ws[ty][tx] = lut[codes[idx]] * absmax[idx >> 6];
    __syncthreads();
#pragma unroll
    for (int kk = 0; kk < 16; ++kk) acc += xs[ty][kk] * ws[tx][kk];
    __syncthreads();
  }
  out[(size_t)m * OUT_F + n0 + tx] = acc;
}

// ---------------------------------------------------------------------------
extern "C" void kernel_launch(void* const* d_in, const int* in_sizes, int n_in,
                              void* d_out, int out_size, void* d_ws, size_t ws_size,
                              hipStream_t stream) {
  const float* x      = (const float*)d_in[0];  // [4,2048,4096] fp32
  const int*   codes  = (const int*)d_in[1];    // [11008,4096] int32 in [0,16)
  const float* absmax = (const float*)d_in[2];  // [704512] fp32
  float* out = (float*)d_out;                   // [4,2048,11008] fp32

  const size_t wBytes = (size_t)OUT_F * IN_F * 2;  // 90,177,536
  const size_t xBytes = (size_t)M_TOT * IN_F * 2;  // 67,108,864

  if (ws_size >= wBytes + xBytes) {
    u16* wq = (u16*)d_ws;
    u16* xq = (u16*)((char*)d_ws + wBytes);

    const int n8w = OUT_F * IN_F / 8;
    dequant_w_kernel<<<(n8w + 255) / 256, 256, 0, stream>>>(
        codes, absmax, (uint4*)wq, n8w);

    const int n8x = M_TOT * IN_F / 8;
    convert_x_kernel<<<(n8x + 255) / 256, 256, 0, stream>>>(
        (const float4*)x, (uint4*)xq, n8x);

    const int nwg = (M_TOT / 128) * (OUT_F / 256);  // 64 * 43 = 2752
    gemm128x256_bt_bf16_kernel<<<nwg, 256, 0, stream>>>(xq, wq, out);
  } else {
    dim3 blk(16, 16);
    dim3 grid(OUT_F / 16, M_TOT / 16);    // (688, 512)
    fallback_kernel<<<grid, blk, 0, stream>>>(x, codes, absmax, out);
  }
}